// Round 6
// baseline (1245.389 us; speedup 1.0000x reference)
//
#include <hip/hip_runtime.h>

typedef __attribute__((ext_vector_type(8))) short short8;
typedef __attribute__((ext_vector_type(4))) float f32x4;
typedef __attribute__((ext_vector_type(4))) float f4v;
typedef unsigned short u16;
typedef unsigned int u32;

#define NPTS 65536
#define CCH 512
#define GDIM 66
#define GDIM2 (66*66)
#define CAPO 18432          // per-offset compacted-row capacity
#define TPO 72              // tiles per offset = CAPO/256

__device__ __forceinline__ u16 f2bf(float f) {
    u32 u = __builtin_bit_cast(u32, f);
    u32 r = (u + 0x7fffu + ((u >> 16) & 1u)) >> 16;
    return (u16)r;
}
__device__ __forceinline__ float bf2f(u16 h) {
    u32 u = ((u32)h) << 16;
    return __builtin_bit_cast(float, u);
}
__device__ __forceinline__ void gld16(const void* g, void* l) {
    __builtin_amdgcn_global_load_lds((const __attribute__((address_space(1))) void*)g,
                                     (__attribute__((address_space(3))) void*)l, 16, 0, 0);
}

// Deep-pipeline sync: counted vmcnt BEFORE raw barrier (per-wave retire => cross-wave
// LDS visibility after barrier). sched_barrier+memory clobber pin compiler ordering.
#define PIPE_WAIT(rem)                                                        \
    __builtin_amdgcn_sched_barrier(0);                                        \
    if ((rem) > 2)       asm volatile("s_waitcnt vmcnt(8)" ::: "memory");     \
    else if ((rem) == 2) asm volatile("s_waitcnt vmcnt(4)" ::: "memory");     \
    else                 asm volatile("s_waitcnt vmcnt(0)" ::: "memory");     \
    __builtin_amdgcn_s_barrier();                                             \
    __builtin_amdgcn_sched_barrier(0);

// ---------------- setup kernels ----------------

__global__ void scatter_vox(const int* __restrict__ coords, int* __restrict__ grid) {
    int i = blockIdx.x * 256 + threadIdx.x;
    if (i < NPTS) {
        int c0 = coords[3*i], c1 = coords[3*i+1], c2 = coords[3*i+2];
        grid[(c0+1)*GDIM2 + (c1+1)*GDIM + (c2+1)] = i;
    }
}

__global__ void cast_bf16(const float* __restrict__ in, u16* __restrict__ out, int n8) {
    int i = blockIdx.x * 256 + threadIdx.x;
    if (i >= n8) return;
    f4v a = *(const f4v*)(in + (size_t)i*8);
    f4v b = *(const f4v*)(in + (size_t)i*8 + 4);
    short8 o;
    #pragma unroll
    for (int j = 0; j < 4; ++j) { o[j] = (short)f2bf(a[j]); o[j+4] = (short)f2bf(b[j]); }
    *(short8*)(out + (size_t)i*8) = o;
}

// in: f32 [R][Cc] row-major, out: bf16 [Cc][R]
__global__ void transpose_cast(const float* __restrict__ in, u16* __restrict__ out,
                               int R, int Cc) {
    __shared__ float tile[32][33];
    size_t moff = (size_t)blockIdx.z * R * Cc;
    in += moff; out += moff;
    int tx = threadIdx.x, ty = threadIdx.y;
    #pragma unroll
    for (int j = 0; j < 4; ++j) {
        int r = blockIdx.y*32 + ty + j*8;
        int c = blockIdx.x*32 + tx;
        tile[ty + j*8][tx] = in[(size_t)r*Cc + c];
    }
    __syncthreads();
    #pragma unroll
    for (int j = 0; j < 4; ++j) {
        int orow = blockIdx.x*32 + ty + j*8;
        int ocol = blockIdx.y*32 + tx;
        out[(size_t)orow*R + ocol] = f2bf(tile[tx][ty + j*8]);
    }
}

// ---------------- compaction: count -> scan -> fill (+ inverse posMap) ----------------

__device__ __forceinline__ int nbr_lookup(const int* coords, const int* grid, int i, int o) {
    int dx = o / 9, dy = (o / 3) % 3, dz = o % 3;
    int c0 = coords[3*i], c1 = coords[3*i+1], c2 = coords[3*i+2];
    return grid[(c0+dx)*GDIM2 + (c1+dy)*GDIM + (c2+dz)];
}

__global__ __launch_bounds__(256) void count_valid(const int* __restrict__ coords,
        const int* __restrict__ grid, int* __restrict__ blockCnt) {
    int o1 = blockIdx.y;
    int o = o1 + (o1 >= 13);
    int i = blockIdx.x*256 + threadIdx.x;
    int v = nbr_lookup(coords, grid, i, o);
    unsigned long long b = __ballot(v >= 0);
    __shared__ int wc[4];
    if ((threadIdx.x & 63) == 0) wc[threadIdx.x >> 6] = __popcll(b);
    __syncthreads();
    if (threadIdx.x == 0)
        blockCnt[o1*256 + blockIdx.x] = wc[0]+wc[1]+wc[2]+wc[3];
}

__global__ __launch_bounds__(256) void scan_kernel(const int* __restrict__ blockCnt,
        int* __restrict__ blockOff, int* __restrict__ cnt) {
    int t = threadIdx.x, lane = t & 63, w = t >> 6;
    __shared__ int wsum[4];
    for (int o1 = 0; o1 < 26; ++o1) {
        int v = blockCnt[o1*256 + t];
        int x = v;
        #pragma unroll
        for (int s = 1; s < 64; s <<= 1) {
            int y = __shfl_up(x, s);
            if (lane >= s) x += y;
        }
        if (lane == 63) wsum[w] = x;
        __syncthreads();
        int base = 0;
        for (int k = 0; k < w; ++k) base += wsum[k];
        blockOff[o1*256 + t] = base + x - v;
        if (t == 255) cnt[o1] = base + x;
        __syncthreads();
    }
}

__global__ __launch_bounds__(256) void fill_kernel(const int* __restrict__ coords,
        const int* __restrict__ grid, const int* __restrict__ blockOff,
        int* __restrict__ srcIdx, int* __restrict__ posMap) {
    int o1 = blockIdx.y;
    int o = o1 + (o1 >= 13);
    int i = blockIdx.x*256 + threadIdx.x;
    int v = nbr_lookup(coords, grid, i, o);
    bool valid = v >= 0;
    unsigned long long b = __ballot(valid);
    int lane = threadIdx.x & 63, w = threadIdx.x >> 6;
    __shared__ int wc[4];
    if (lane == 0) wc[w] = __popcll(b);
    __syncthreads();
    int base = blockOff[o1*256 + blockIdx.x];
    for (int k = 0; k < w; ++k) base += wc[k];
    int pre = __popcll(b & ((1ull << lane) - 1ull));
    int pos = base + pre;
    bool ok = valid && pos < CAPO;
    if (ok) srcIdx[o1*CAPO + pos] = v;
    posMap[(size_t)o1*NPTS + i] = ok ? pos : -1;
}

// ---------------- 256x256 deep-pipelined GEMM (BK=32, 4 LDS bufs, 3-deep prefetch) ----
// MODE 1: mlp1 — outb bf16 = silu(acc+bias)
// MODE 2: mlp2 — outf f32 = acc+bias+resid (first) or acc+outf
// MODE 3: conv center — outb bf16 = acc+bias
// XCD-grouped block map: NX col-tiles of one row-group consecutive on one XCD.

template<int MODE, int NX>
__global__ __launch_bounds__(512, 2) void gemm256(
    const u16* __restrict__ A, int lda,
    const u16* __restrict__ BT, int ldb,
    int nT,                                  // K/32
    const float* __restrict__ bias,
    const float* __restrict__ resid,
    float* __restrict__ outf, u16* __restrict__ outb, int ldout, int first)
{
    __shared__ __align__(1024) char lds[131072];   // 4 bufs x (A 16KB + B 16KB)
    const int L = blockIdx.x;
    const int cx = L & 7, tt = L >> 3;
    const int bx = tt % NX;
    const int by = cx + 8 * (tt / NX);
    const int row0 = by * 256, col0 = bx * 256;

    const int tid = threadIdx.x;
    const int w = tid >> 6, lane = tid & 63;
    const int wm = w >> 2, wn = w & 3;
    const int csrc = (tid & 3) ^ ((tid >> 2) & 3);   // source chunk (inverse swizzle)
    const int r2 = tid >> 2;                          // 0..127

    const u16* aP0 = A + (size_t)(row0 + r2) * lda + csrc*8;
    const u16* aP1 = aP0 + (size_t)128 * lda;
    const u16* bP0 = BT + (size_t)(col0 + r2) * ldb + csrc*8;
    const u16* bP1 = bP0 + (size_t)128 * ldb;

    f32x4 acc[8][4] = {};

    auto stage = [&](int buf, int t) {
        char* la = lds + buf*32768;
        char* lb = la + 16384;
        int k0 = t * 32;
        gld16(aP0 + k0, la + tid*16);
        gld16(aP1 + k0, la + 8192 + tid*16);
        gld16(bP0 + k0, lb + tid*16);
        gld16(bP1 + k0, lb + 8192 + tid*16);
    };

    const int chx = (lane >> 4) ^ (lane & 3);        // read-side swizzled chunk
    const int rbase = lane & 15;

    stage(0, 0); stage(1, 1); stage(2, 2);

    #pragma unroll 1
    for (int t = 0; t < nT; ++t) {
        PIPE_WAIT(nT - t);
        if (t + 3 < nT) stage((t + 3) & 3, t + 3);
        const char* la = lds + (t & 3)*32768;
        const char* lb = la + 16384;
        short8 bfr[4];
        #pragma unroll
        for (int j = 0; j < 4; ++j)
            bfr[j] = *(const short8*)(void*)(lb + (wn*64 + j*16 + rbase)*64 + chx*16);
        __builtin_amdgcn_s_setprio(1);
        #pragma unroll
        for (int f = 0; f < 8; ++f) {
            short8 afr = *(const short8*)(void*)(la + (wm*128 + f*16 + rbase)*64 + chx*16);
            #pragma unroll
            for (int j = 0; j < 4; ++j)
                acc[f][j] = __builtin_amdgcn_mfma_f32_16x16x32_bf16(afr, bfr[j], acc[f][j], 0, 0, 0);
        }
        __builtin_amdgcn_s_setprio(0);
    }

    #pragma unroll
    for (int f = 0; f < 8; ++f) {
        int r = row0 + wm*128 + f*16 + (lane >> 4)*4;
        #pragma unroll
        for (int j = 0; j < 4; ++j) {
            int c = col0 + wn*64 + j*16 + (lane & 15);
            float bv = bias[c];
            #pragma unroll
            for (int q = 0; q < 4; ++q) {
                float v = acc[f][j][q];
                if constexpr (MODE == 1) {
                    float val = v + bv;
                    float sg = 1.f / (1.f + __expf(-val));
                    outb[(size_t)(r+q)*ldout + c] = f2bf(val * sg);
                } else if constexpr (MODE == 2) {
                    size_t ix = (size_t)(r+q)*512 + c;
                    outf[ix] = first ? (v + bv + resid[ix]) : (v + outf[ix]);
                } else {  // MODE 3
                    outb[(size_t)(r+q)*ldout + c] = f2bf(v + bv);
                }
            }
        }
    }
}

// ---------------- comp GEMM: compacted rows -> bf16 contribution rows (deep pipeline) --

__global__ __launch_bounds__(512, 2) void comp_gemm(
    const u16* __restrict__ fb,
    const int* __restrict__ srcIdx,
    const int* __restrict__ cnt,
    const u16* __restrict__ wcT,
    u16* __restrict__ comp,
    int o1base)
{
    __shared__ __align__(1024) char lds[131072];
    const int L = blockIdx.x;
    const int cx = L & 7, tt = L >> 3;
    const int bx = tt & 1;                 // col tile
    const int y  = cx + 8 * (tt >> 1);     // 0..935
    const int o1loc = y / TPO, mt = y % TPO;
    const int o1 = o1base + o1loc;
    const int n = cnt[o1];
    if (mt * 256 >= n) return;             // block-uniform, before any barrier
    const int o = o1 + (o1 >= 13);
    const int tid = threadIdx.x;
    const int w = tid >> 6, lane = tid & 63;
    const int wm = w >> 2, wn = w & 3;
    const int col0 = bx * 256;
    const int csrc = (tid & 3) ^ ((tid >> 2) & 3);
    const int r2 = tid >> 2;

    const int* sIdx = srcIdx + o1*CAPO + mt*256;
    const u16* wb = wcT + ((size_t)o << 18);

    int m0 = mt*256 + r2;
    int src0 = (m0       < n) ? sIdx[r2]       : NPTS;
    int src1 = (m0 + 128 < n) ? sIdx[r2 + 128] : NPTS;
    const u16* aP0 = fb + (size_t)src0*512 + csrc*8;
    const u16* aP1 = fb + (size_t)src1*512 + csrc*8;
    const u16* bP0 = wb + (size_t)(col0 + r2)*512 + csrc*8;
    const u16* bP1 = bP0 + (size_t)128*512;

    f32x4 acc[8][4] = {};

    auto stage = [&](int buf, int t) {
        char* la = lds + buf*32768;
        char* lb = la + 16384;
        int k0 = t * 32;
        gld16(aP0 + k0, la + tid*16);
        gld16(aP1 + k0, la + 8192 + tid*16);
        gld16(bP0 + k0, lb + tid*16);
        gld16(bP1 + k0, lb + 8192 + tid*16);
    };

    const int chx = (lane >> 4) ^ (lane & 3);
    const int rbase = lane & 15;
    const int nT = 16;                      // K = 512

    stage(0, 0); stage(1, 1); stage(2, 2);

    #pragma unroll 1
    for (int t = 0; t < nT; ++t) {
        PIPE_WAIT(nT - t);
        if (t + 3 < nT) stage((t + 3) & 3, t + 3);
        const char* la = lds + (t & 3)*32768;
        const char* lb = la + 16384;
        short8 bfr[4];
        #pragma unroll
        for (int j = 0; j < 4; ++j)
            bfr[j] = *(const short8*)(void*)(lb + (wn*64 + j*16 + rbase)*64 + chx*16);
        __builtin_amdgcn_s_setprio(1);
        #pragma unroll
        for (int f = 0; f < 8; ++f) {
            short8 afr = *(const short8*)(void*)(la + (wm*128 + f*16 + rbase)*64 + chx*16);
            #pragma unroll
            for (int j = 0; j < 4; ++j)
                acc[f][j] = __builtin_amdgcn_mfma_f32_16x16x32_bf16(afr, bfr[j], acc[f][j], 0, 0, 0);
        }
        __builtin_amdgcn_s_setprio(0);
    }

    #pragma unroll
    for (int f = 0; f < 8; ++f) {
        #pragma unroll
        for (int q = 0; q < 4; ++q) {
            int rl = wm*128 + f*16 + (lane >> 4)*4 + q;
            if (mt*256 + rl < n) {
                u16* cr = comp + ((size_t)(o1loc*CAPO + mt*256 + rl))*512
                               + col0 + wn*64 + (lane & 15);
                #pragma unroll
                for (int j = 0; j < 4; ++j)
                    cr[j*16] = f2bf(acc[f][j][q]);
            }
        }
    }
}

// ---------------- gather-reduce: h(bf16) += contributions; FINAL fuses LN ----------------

template<int FINAL>
__global__ __launch_bounds__(512) void reduce_kernel(
    const u16* __restrict__ comp, const int* __restrict__ posMap,
    int o1base, int nOff,
    u16* __restrict__ h,
    const float* __restrict__ g, const float* __restrict__ bb,
    u16* __restrict__ nf)
{
    int w = threadIdx.x >> 6, lane = threadIdx.x & 63;
    int i = blockIdx.x*8 + w;
    u16* hr = h + (size_t)i*512 + lane*8;
    short8 hv = *(const short8*)hr;
    float x[8];
    #pragma unroll
    for (int j = 0; j < 8; ++j) x[j] = bf2f((u16)hv[j]);

    #pragma unroll 1
    for (int k = 0; k < nOff; ++k) {
        int pos = posMap[(size_t)(o1base + k)*NPTS + i];
        if (pos >= 0) {   // wave-uniform branch
            short8 cv = *(const short8*)(comp + ((size_t)(k*CAPO + pos))*512 + lane*8);
            #pragma unroll
            for (int j = 0; j < 8; ++j) x[j] += bf2f((u16)cv[j]);
        }
    }

    if constexpr (!FINAL) {
        short8 o;
        #pragma unroll
        for (int j = 0; j < 8; ++j) o[j] = (short)f2bf(x[j]);
        *(short8*)hr = o;
    } else {
        float s = 0.f, ss = 0.f;
        #pragma unroll
        for (int j = 0; j < 8; ++j) { s += x[j]; ss += x[j]*x[j]; }
        #pragma unroll
        for (int m = 1; m < 64; m <<= 1) { s += __shfl_xor(s, m); ss += __shfl_xor(ss, m); }
        float mu = s * (1.f/512.f);
        float var = ss * (1.f/512.f) - mu*mu;
        float inv = rsqrtf(var + 1e-6f);
        short8 o;
        #pragma unroll
        for (int j = 0; j < 8; ++j) {
            int c = lane*8 + j;
            o[j] = (short)f2bf((x[j] - mu) * inv * g[c] + bb[c]);
        }
        *(short8*)(nf + (size_t)i*512 + lane*8) = o;
    }
}

// ---------------- launch ----------------

extern "C" void kernel_launch(void* const* d_in, const int* in_sizes, int n_in,
                              void* d_out, int out_size, void* d_ws, size_t ws_size,
                              hipStream_t stream) {
    const float* feats  = (const float*)d_in[0];
    const int*   coords = (const int*)d_in[1];
    const float* conv_w = (const float*)d_in[2];
    const float* conv_b = (const float*)d_in[3];
    const float* ln_g   = (const float*)d_in[4];
    const float* ln_b   = (const float*)d_in[5];
    const float* w1     = (const float*)d_in[6];
    const float* b1     = (const float*)d_in[7];
    const float* w2     = (const float*)d_in[8];
    const float* b2     = (const float*)d_in[9];
    float* out = (float*)d_out;
    char* ws = (char*)d_ws;

    size_t off = 0;
    auto take = [&](size_t bytes) -> void* {
        void* p = ws + off;
        off += (bytes + 1023) & ~(size_t)1023;
        return p;
    };
    int* grid_i   = (int*)take((size_t)GDIM*GDIM2*4);
    u16* wcT      = (u16*)take(27ull*512*512*2);
    u16* w1T      = (u16*)take(2048ull*512*2);
    u16* w2T      = (u16*)take(512ull*2048*2);
    u16* fb       = (u16*)take((NPTS+1ull)*512*2);
    int* srcIdx   = (int*)take(26ull*CAPO*4);
    int* posMap   = (int*)take(26ull*NPTS*4);
    int* blockCnt = (int*)take(26*256*4);
    int* blockOff = (int*)take(26*256*4);
    int* cnt      = (int*)take(26*4);
    u16* comp     = (u16*)take(13ull*CAPO*512*2);   // per-pass contribution rows (bf16)
    u16* h        = (u16*)take(67108864ull);        // h bf16 [N][512]
    u16* g1 = h;                                    // overlays h (dead after reduce<1>)
    bool fused = (off + 201326592ull) <= ws_size;   // need [N][2048] total for g1
    if (fused) take(201326592ull);
    else       take(67108864ull);
    u16* nf = fb;                                   // reused after conv consumes fb

    hipMemsetAsync(grid_i, 0xFF, (size_t)GDIM*GDIM2*4, stream);
    hipMemsetAsync(fb + (size_t)NPTS*512, 0, 512*2, stream);

    scatter_vox<<<NPTS/256, 256, 0, stream>>>(coords, grid_i);
    cast_bf16<<<(NPTS*CCH/8)/256, 256, 0, stream>>>(feats, fb, NPTS*CCH/8);
    transpose_cast<<<dim3(16,16,27), dim3(32,8), 0, stream>>>(conv_w, wcT, 512, 512);
    transpose_cast<<<dim3(64,16,1),  dim3(32,8), 0, stream>>>(w1, w1T, 512, 2048);
    transpose_cast<<<dim3(16,64,1),  dim3(32,8), 0, stream>>>(w2, w2T, 2048, 512);

    count_valid<<<dim3(256,26), 256, 0, stream>>>(coords, grid_i, blockCnt);
    scan_kernel<<<1, 256, 0, stream>>>(blockCnt, blockOff, cnt);
    fill_kernel<<<dim3(256,26), 256, 0, stream>>>(coords, grid_i, blockOff, srcIdx, posMap);

    // center offset (o=13): dense, writes h bf16 = fb @ W13^T + bias (h init)
    gemm256<3,2><<<512, 512, 0, stream>>>(
        fb, 512, wcT + (13ull << 18), 512, 16, conv_b, nullptr, nullptr, h, 512, 0);

    // two passes of 13 non-center offsets: compact GEMM -> gather reduce (no atomics)
    comp_gemm<<<2*TPO*13, 512, 0, stream>>>(fb, srcIdx, cnt, wcT, comp, 0);
    reduce_kernel<0><<<NPTS/8, 512, 0, stream>>>(comp, posMap, 0, 13, h, nullptr, nullptr, nullptr);
    comp_gemm<<<2*TPO*13, 512, 0, stream>>>(fb, srcIdx, cnt, wcT, comp, 13);
    reduce_kernel<1><<<NPTS/8, 512, 0, stream>>>(comp, posMap, 13, 13, h, ln_g, ln_b, nf);

    if (fused) {
        gemm256<1,8><<<2048, 512, 0, stream>>>(
            nf, 512, w1T, 512, 16, b1, nullptr, nullptr, g1, 2048, 0);
        gemm256<2,2><<<512, 512, 0, stream>>>(
            g1, 2048, w2T, 2048, 64, b2, feats, out, nullptr, 512, 1);
    } else {
        for (int half = 0; half < 2; ++half) {
            gemm256<1,4><<<1024, 512, 0, stream>>>(
                nf, 512, w1T + (size_t)half*1024*512, 512, 16,
                b1 + half*1024, nullptr, nullptr, g1, 1024, 0);
            gemm256<2,2><<<512, 512, 0, stream>>>(
                g1, 1024, w2T + half*1024, 2048, 32,
                b2, feats, out, nullptr, 512, half == 0);
        }
    }
}

// Round 7
// 1228.656 us; speedup vs baseline: 1.0136x; 1.0136x over previous
//
#include <hip/hip_runtime.h>

typedef __attribute__((ext_vector_type(8))) short short8;
typedef __attribute__((ext_vector_type(4))) float f32x4;
typedef __attribute__((ext_vector_type(4))) float f4v;
typedef unsigned short u16;
typedef unsigned int u32;

#define NPTS 65536
#define CCH 512
#define GDIM 66
#define GDIM2 (66*66)
#define CAPO 18432          // per-offset compacted-row capacity
#define TPO 72              // tiles per offset = CAPO/256

__device__ __forceinline__ u16 f2bf(float f) {
    u32 u = __builtin_bit_cast(u32, f);
    u32 r = (u + 0x7fffu + ((u >> 16) & 1u)) >> 16;
    return (u16)r;
}
__device__ __forceinline__ float bf2f(u16 h) {
    u32 u = ((u32)h) << 16;
    return __builtin_bit_cast(float, u);
}
__device__ __forceinline__ void gld16(const void* g, void* l) {
    __builtin_amdgcn_global_load_lds((const __attribute__((address_space(1))) void*)g,
                                     (__attribute__((address_space(3))) void*)l, 16, 0, 0);
}

#define VMW4 asm volatile("s_waitcnt vmcnt(4)" ::: "memory")
#define LGK0 asm volatile("s_waitcnt lgkmcnt(0)" ::: "memory")
#define SBAR __builtin_amdgcn_s_barrier()
#define SCHB __builtin_amdgcn_sched_barrier(0)

// ---------------- setup kernels ----------------

__global__ void scatter_vox(const int* __restrict__ coords, int* __restrict__ grid) {
    int i = blockIdx.x * 256 + threadIdx.x;
    if (i < NPTS) {
        int c0 = coords[3*i], c1 = coords[3*i+1], c2 = coords[3*i+2];
        grid[(c0+1)*GDIM2 + (c1+1)*GDIM + (c2+1)] = i;
    }
}

__global__ void cast_bf16(const float* __restrict__ in, u16* __restrict__ out, int n8) {
    int i = blockIdx.x * 256 + threadIdx.x;
    if (i >= n8) return;
    f4v a = *(const f4v*)(in + (size_t)i*8);
    f4v b = *(const f4v*)(in + (size_t)i*8 + 4);
    short8 o;
    #pragma unroll
    for (int j = 0; j < 4; ++j) { o[j] = (short)f2bf(a[j]); o[j+4] = (short)f2bf(b[j]); }
    *(short8*)(out + (size_t)i*8) = o;
}

// in: f32 [R][Cc] row-major, out: bf16 [Cc][R]
__global__ void transpose_cast(const float* __restrict__ in, u16* __restrict__ out,
                               int R, int Cc) {
    __shared__ float tile[32][33];
    size_t moff = (size_t)blockIdx.z * R * Cc;
    in += moff; out += moff;
    int tx = threadIdx.x, ty = threadIdx.y;
    #pragma unroll
    for (int j = 0; j < 4; ++j) {
        int r = blockIdx.y*32 + ty + j*8;
        int c = blockIdx.x*32 + tx;
        tile[ty + j*8][tx] = in[(size_t)r*Cc + c];
    }
    __syncthreads();
    #pragma unroll
    for (int j = 0; j < 4; ++j) {
        int orow = blockIdx.x*32 + ty + j*8;
        int ocol = blockIdx.y*32 + tx;
        out[(size_t)orow*R + ocol] = f2bf(tile[tx][ty + j*8]);
    }
}

// ---------------- compaction: count -> scan -> fill (+ inverse posMap) ----------------

__device__ __forceinline__ int nbr_lookup(const int* coords, const int* grid, int i, int o) {
    int dx = o / 9, dy = (o / 3) % 3, dz = o % 3;
    int c0 = coords[3*i], c1 = coords[3*i+1], c2 = coords[3*i+2];
    return grid[(c0+dx)*GDIM2 + (c1+dy)*GDIM + (c2+dz)];
}

__global__ __launch_bounds__(256) void count_valid(const int* __restrict__ coords,
        const int* __restrict__ grid, int* __restrict__ blockCnt) {
    int o1 = blockIdx.y;
    int o = o1 + (o1 >= 13);
    int i = blockIdx.x*256 + threadIdx.x;
    int v = nbr_lookup(coords, grid, i, o);
    unsigned long long b = __ballot(v >= 0);
    __shared__ int wc[4];
    if ((threadIdx.x & 63) == 0) wc[threadIdx.x >> 6] = __popcll(b);
    __syncthreads();
    if (threadIdx.x == 0)
        blockCnt[o1*256 + blockIdx.x] = wc[0]+wc[1]+wc[2]+wc[3];
}

__global__ __launch_bounds__(256) void scan_kernel(const int* __restrict__ blockCnt,
        int* __restrict__ blockOff, int* __restrict__ cnt) {
    int t = threadIdx.x, lane = t & 63, w = t >> 6;
    __shared__ int wsum[4];
    for (int o1 = 0; o1 < 26; ++o1) {
        int v = blockCnt[o1*256 + t];
        int x = v;
        #pragma unroll
        for (int s = 1; s < 64; s <<= 1) {
            int y = __shfl_up(x, s);
            if (lane >= s) x += y;
        }
        if (lane == 63) wsum[w] = x;
        __syncthreads();
        int base = 0;
        for (int k = 0; k < w; ++k) base += wsum[k];
        blockOff[o1*256 + t] = base + x - v;
        if (t == 255) cnt[o1] = base + x;
        __syncthreads();
    }
}

__global__ __launch_bounds__(256) void fill_kernel(const int* __restrict__ coords,
        const int* __restrict__ grid, const int* __restrict__ blockOff,
        int* __restrict__ srcIdx, int* __restrict__ posMap) {
    int o1 = blockIdx.y;
    int o = o1 + (o1 >= 13);
    int i = blockIdx.x*256 + threadIdx.x;
    int v = nbr_lookup(coords, grid, i, o);
    bool valid = v >= 0;
    unsigned long long b = __ballot(valid);
    int lane = threadIdx.x & 63, w = threadIdx.x >> 6;
    __shared__ int wc[4];
    if (lane == 0) wc[w] = __popcll(b);
    __syncthreads();
    int base = blockOff[o1*256 + blockIdx.x];
    for (int k = 0; k < w; ++k) base += wc[k];
    int pre = __popcll(b & ((1ull << lane) - 1ull));
    int pos = base + pre;
    bool ok = valid && pos < CAPO;
    if (ok) srcIdx[o1*CAPO + pos] = v;
    posMap[(size_t)o1*NPTS + i] = ok ? pos : -1;
}

// ============ phase-pipelined 256x256 GEMM engine ============
// K-tiles of 64 split into K-halves of 32. LDS: A slots 0..64KB, B slots 64..128KB,
// 4 x 16KB each (slot = (2t+kh)&3). Stage stream S[i]: i&1 = matrix, (i>>1)&1 = khalf,
// i>>2 = tile. Phase P=4t+q stages S[6+P]; uniform vmcnt(4) -> 3-phase landing lead.
// Phase q: kk=q>>1, M-half=q&1: 4 A-frag reads (+4 B at even q, reused), 16 MFMA.

#define GEMM_PIPE_BODY(NTILES)                                                         \
    const int g_ = lane >> 4, rbase = lane & 15;                                       \
    const int chxC = g_ ^ ((lane >> 1) & 3);                                           \
    f32x4 acc[8][4] = {};                                                              \
    short8 bfr[4];                                                                     \
    auto stageS = [&](int i) {                                                         \
        int tt = i >> 2, mtx = i & 1, kh = (i >> 1) & 1;                               \
        char* dst = lds + mtx*65536 + (((tt<<1) + kh) & 3)*16384;                      \
        int koff = tt*64 + kh*32;                                                      \
        if (mtx == 0) { gld16(aP0 + koff, dst + tid*16);                               \
                        gld16(aP1 + koff, dst + 8192 + tid*16); }                      \
        else          { gld16(bP0 + koff, dst + tid*16);                               \
                        gld16(bP1 + koff, dst + 8192 + tid*16); }                      \
    };                                                                                 \
    for (int i = 0; i < 6; ++i) stageS(i);                                             \
    SCHB; VMW4; SBAR;                                                                  \
    _Pragma("unroll 1")                                                                \
    for (int t = 0; t < (NTILES); ++t) {                                               \
        _Pragma("unroll")                                                              \
        for (int q = 0; q < 4; ++q) {                                                  \
            const int kk = q >> 1;                                                     \
            const char* la = lds + (((t<<1) + kk) & 3)*16384;                          \
            const char* lb = la + 65536;                                               \
            if ((q & 1) == 0) {                                                        \
                _Pragma("unroll")                                                      \
                for (int j = 0; j < 4; ++j)                                            \
                    bfr[j] = *(const short8*)(const void*)                             \
                        (lb + (wn*64 + j*16 + rbase)*64 + chxC*16);                    \
            }                                                                          \
            short8 afr[4];                                                             \
            _Pragma("unroll")                                                          \
            for (int f4 = 0; f4 < 4; ++f4)                                             \
                afr[f4] = *(const short8*)(const void*)                                \
                    (la + (wm*128 + ((q&1)*4 + f4)*16 + rbase)*64 + chxC*16);          \
            int si = 6 + t*4 + q;                                                      \
            if (si < (NTILES)*4) stageS(si);                                           \
            SCHB; VMW4; SBAR; LGK0; SCHB;                                              \
            __builtin_amdgcn_s_setprio(1);                                             \
            _Pragma("unroll")                                                          \
            for (int f4 = 0; f4 < 4; ++f4)                                             \
                _Pragma("unroll")                                                      \
                for (int j = 0; j < 4; ++j)                                            \
                    acc[(q&1)*4 + f4][j] = __builtin_amdgcn_mfma_f32_16x16x32_bf16(    \
                        afr[f4], bfr[j], acc[(q&1)*4 + f4][j], 0, 0, 0);               \
            __builtin_amdgcn_s_setprio(0);                                             \
            SBAR;                                                                      \
        }                                                                              \
    }

// MODE 1: mlp1 — outb bf16 = silu(acc+bias)
// MODE 2: mlp2 — outf f32 = acc+bias+resid (first) or acc+outf
// MODE 3: conv center — outb bf16 = acc+bias
template<int MODE, int NX>
__global__ __launch_bounds__(512, 2) void gemm256(
    const u16* __restrict__ A, int lda,
    const u16* __restrict__ BT, int ldb,
    int nT,
    const float* __restrict__ bias,
    const float* __restrict__ resid,
    float* __restrict__ outf, u16* __restrict__ outb, int ldout, int first)
{
    __shared__ __align__(1024) char lds[131072];
    const int L = blockIdx.x;
    const int cx = L & 7, tt0 = L >> 3;
    const int bx = tt0 % NX;
    const int by = cx + 8 * (tt0 / NX);
    const int row0 = by * 256, col0 = bx * 256;

    const int tid = threadIdx.x;
    const int w = tid >> 6, lane = tid & 63;
    const int wm = w >> 2, wn = w & 3;
    const int csrc = (tid & 3) ^ ((tid >> 3) & 3);
    const int rI = tid >> 2;                       // 0..127

    const u16* aP0 = A + (size_t)(row0 + rI) * lda + csrc*8;
    const u16* aP1 = aP0 + (size_t)128 * lda;
    const u16* bP0 = BT + (size_t)(col0 + rI) * ldb + csrc*8;
    const u16* bP1 = bP0 + (size_t)128 * ldb;

    GEMM_PIPE_BODY(nT)

    #pragma unroll
    for (int f = 0; f < 8; ++f) {
        int r = row0 + wm*128 + f*16 + (lane >> 4)*4;
        #pragma unroll
        for (int j = 0; j < 4; ++j) {
            int c = col0 + wn*64 + j*16 + (lane & 15);
            float bv = bias[c];
            #pragma unroll
            for (int q = 0; q < 4; ++q) {
                float v = acc[f][j][q];
                if constexpr (MODE == 1) {
                    float val = v + bv;
                    float sg = 1.f / (1.f + __expf(-val));
                    outb[(size_t)(r+q)*ldout + c] = f2bf(val * sg);
                } else if constexpr (MODE == 2) {
                    size_t ix = (size_t)(r+q)*512 + c;
                    outf[ix] = first ? (v + bv + resid[ix]) : (v + outf[ix]);
                } else {  // MODE 3
                    outb[(size_t)(r+q)*ldout + c] = f2bf(v + bv);
                }
            }
        }
    }
}

// comp GEMM: compacted rows -> bf16 contribution rows (no atomics), pipelined engine.
__global__ __launch_bounds__(512, 2) void comp_gemm(
    const u16* __restrict__ fb,
    const int* __restrict__ srcIdx,
    const int* __restrict__ cnt,
    const u16* __restrict__ wcT,
    u16* __restrict__ comp,
    int o1base)
{
    __shared__ __align__(1024) char lds[131072];
    const int L = blockIdx.x;
    const int cx = L & 7, tt0 = L >> 3;
    const int bx = tt0 & 1;                 // col tile
    const int y  = cx + 8 * (tt0 >> 1);     // 0..935
    const int o1loc = y / TPO, mt = y % TPO;
    const int o1 = o1base + o1loc;
    const int n = cnt[o1];
    if (mt * 256 >= n) return;              // block-uniform, before any barrier
    const int o = o1 + (o1 >= 13);
    const int tid = threadIdx.x;
    const int w = tid >> 6, lane = tid & 63;
    const int wm = w >> 2, wn = w & 3;
    const int col0 = bx * 256;
    const int csrc = (tid & 3) ^ ((tid >> 3) & 3);
    const int rI = tid >> 2;

    const int* sIdx = srcIdx + o1*CAPO + mt*256;
    const u16* wb = wcT + ((size_t)o << 18);

    int m0 = mt*256 + rI;
    int src0 = (m0       < n) ? sIdx[rI]       : NPTS;   // zero-row fallback
    int src1 = (m0 + 128 < n) ? sIdx[rI + 128] : NPTS;
    const u16* aP0 = fb + (size_t)src0*512 + csrc*8;
    const u16* aP1 = fb + (size_t)src1*512 + csrc*8;
    const u16* bP0 = wb + (size_t)(col0 + rI)*512 + csrc*8;
    const u16* bP1 = bP0 + (size_t)128*512;

    GEMM_PIPE_BODY(8)

    #pragma unroll
    for (int f = 0; f < 8; ++f) {
        #pragma unroll
        for (int q = 0; q < 4; ++q) {
            int rl = wm*128 + f*16 + (lane >> 4)*4 + q;
            if (mt*256 + rl < n) {
                u16* cr = comp + ((size_t)(o1loc*CAPO + mt*256 + rl))*512
                               + col0 + wn*64 + (lane & 15);
                #pragma unroll
                for (int j = 0; j < 4; ++j)
                    cr[j*16] = f2bf(acc[f][j][q]);
            }
        }
    }
}

// ---------------- gather-reduce: h(bf16) += contributions; FINAL fuses LN ----------------

template<int FINAL>
__global__ __launch_bounds__(512) void reduce_kernel(
    const u16* __restrict__ comp, const int* __restrict__ posMap,
    int o1base, int nOff,
    u16* __restrict__ h,
    const float* __restrict__ g, const float* __restrict__ bb,
    u16* __restrict__ nf)
{
    int w = threadIdx.x >> 6, lane = threadIdx.x & 63;
    int i = blockIdx.x*8 + w;
    u16* hr = h + (size_t)i*512 + lane*8;
    short8 hv = *(const short8*)hr;
    float x[8];
    #pragma unroll
    for (int j = 0; j < 8; ++j) x[j] = bf2f((u16)hv[j]);

    #pragma unroll 1
    for (int k = 0; k < nOff; ++k) {
        int pos = posMap[(size_t)(o1base + k)*NPTS + i];
        if (pos >= 0) {   // wave-uniform branch
            short8 cv = *(const short8*)(comp + ((size_t)(k*CAPO + pos))*512 + lane*8);
            #pragma unroll
            for (int j = 0; j < 8; ++j) x[j] += bf2f((u16)cv[j]);
        }
    }

    if constexpr (!FINAL) {
        short8 o;
        #pragma unroll
        for (int j = 0; j < 8; ++j) o[j] = (short)f2bf(x[j]);
        *(short8*)hr = o;
    } else {
        float s = 0.f, ss = 0.f;
        #pragma unroll
        for (int j = 0; j < 8; ++j) { s += x[j]; ss += x[j]*x[j]; }
        #pragma unroll
        for (int m = 1; m < 64; m <<= 1) { s += __shfl_xor(s, m); ss += __shfl_xor(ss, m); }
        float mu = s * (1.f/512.f);
        float var = ss * (1.f/512.f) - mu*mu;
        float inv = rsqrtf(var + 1e-6f);
        short8 o;
        #pragma unroll
        for (int j = 0; j < 8; ++j) {
            int c = lane*8 + j;
            o[j] = (short)f2bf((x[j] - mu) * inv * g[c] + bb[c]);
        }
        *(short8*)(nf + (size_t)i*512 + lane*8) = o;
    }
}

// ---------------- launch ----------------

extern "C" void kernel_launch(void* const* d_in, const int* in_sizes, int n_in,
                              void* d_out, int out_size, void* d_ws, size_t ws_size,
                              hipStream_t stream) {
    const float* feats  = (const float*)d_in[0];
    const int*   coords = (const int*)d_in[1];
    const float* conv_w = (const float*)d_in[2];
    const float* conv_b = (const float*)d_in[3];
    const float* ln_g   = (const float*)d_in[4];
    const float* ln_b   = (const float*)d_in[5];
    const float* w1     = (const float*)d_in[6];
    const float* b1     = (const float*)d_in[7];
    const float* w2     = (const float*)d_in[8];
    const float* b2     = (const float*)d_in[9];
    float* out = (float*)d_out;
    char* ws = (char*)d_ws;

    size_t off = 0;
    auto take = [&](size_t bytes) -> void* {
        void* p = ws + off;
        off += (bytes + 1023) & ~(size_t)1023;
        return p;
    };
    int* grid_i   = (int*)take((size_t)GDIM*GDIM2*4);
    u16* wcT      = (u16*)take(27ull*512*512*2);
    u16* w1T      = (u16*)take(2048ull*512*2);
    u16* w2T      = (u16*)take(512ull*2048*2);
    u16* fb       = (u16*)take((NPTS+1ull)*512*2);
    int* srcIdx   = (int*)take(26ull*CAPO*4);
    int* posMap   = (int*)take(26ull*NPTS*4);
    int* blockCnt = (int*)take(26*256*4);
    int* blockOff = (int*)take(26*256*4);
    int* cnt      = (int*)take(26*4);
    u16* comp     = (u16*)take(13ull*CAPO*512*2);   // per-pass contribution rows (bf16)
    u16* h        = (u16*)take(67108864ull);        // h bf16 [N][512]
    u16* g1 = h;                                    // overlays h (dead after reduce<1>)
    bool fused = (off + 201326592ull) <= ws_size;   // need [N][2048] total for g1
    if (fused) take(201326592ull);
    else       take(67108864ull);
    u16* nf = fb;                                   // reused after conv consumes fb

    hipMemsetAsync(grid_i, 0xFF, (size_t)GDIM*GDIM2*4, stream);
    hipMemsetAsync(fb + (size_t)NPTS*512, 0, 512*2, stream);

    scatter_vox<<<NPTS/256, 256, 0, stream>>>(coords, grid_i);
    cast_bf16<<<(NPTS*CCH/8)/256, 256, 0, stream>>>(feats, fb, NPTS*CCH/8);
    transpose_cast<<<dim3(16,16,27), dim3(32,8), 0, stream>>>(conv_w, wcT, 512, 512);
    transpose_cast<<<dim3(64,16,1),  dim3(32,8), 0, stream>>>(w1, w1T, 512, 2048);
    transpose_cast<<<dim3(16,64,1),  dim3(32,8), 0, stream>>>(w2, w2T, 2048, 512);

    count_valid<<<dim3(256,26), 256, 0, stream>>>(coords, grid_i, blockCnt);
    scan_kernel<<<1, 256, 0, stream>>>(blockCnt, blockOff, cnt);
    fill_kernel<<<dim3(256,26), 256, 0, stream>>>(coords, grid_i, blockOff, srcIdx, posMap);

    // center offset (o=13): dense, writes h bf16 = fb @ W13^T + bias (h init)
    gemm256<3,2><<<512, 512, 0, stream>>>(
        fb, 512, wcT + (13ull << 18), 512, 8, conv_b, nullptr, nullptr, h, 512, 0);

    // two passes of 13 non-center offsets: compact GEMM -> gather reduce (no atomics)
    comp_gemm<<<2*TPO*13, 512, 0, stream>>>(fb, srcIdx, cnt, wcT, comp, 0);
    reduce_kernel<0><<<NPTS/8, 512, 0, stream>>>(comp, posMap, 0, 13, h, nullptr, nullptr, nullptr);
    comp_gemm<<<2*TPO*13, 512, 0, stream>>>(fb, srcIdx, cnt, wcT, comp, 13);
    reduce_kernel<1><<<NPTS/8, 512, 0, stream>>>(comp, posMap, 13, 13, h, ln_g, ln_b, nf);

    if (fused) {
        gemm256<1,8><<<2048, 512, 0, stream>>>(
            nf, 512, w1T, 512, 8, b1, nullptr, nullptr, g1, 2048, 0);
        gemm256<2,2><<<512, 512, 0, stream>>>(
            g1, 2048, w2T, 2048, 32, b2, feats, out, nullptr, 512, 1);
    } else {
        for (int half = 0; half < 2; ++half) {
            gemm256<1,4><<<1024, 512, 0, stream>>>(
                nf, 512, w1T + (size_t)half*1024*512, 512, 8,
                b1 + half*1024, nullptr, nullptr, g1, 1024, 0);
            gemm256<2,2><<<512, 512, 0, stream>>>(
                g1, 1024, w2T + half*1024, 2048, 16,
                b2, feats, out, nullptr, 512, half == 0);
        }
    }
}

// Round 8
// 1117.615 us; speedup vs baseline: 1.1143x; 1.0994x over previous
//
#include <hip/hip_runtime.h>

typedef __attribute__((ext_vector_type(8))) short short8;
typedef __attribute__((ext_vector_type(4))) float f32x4;
typedef __attribute__((ext_vector_type(4))) float f4v;
typedef unsigned short u16;
typedef unsigned int u32;

#define NPTS 65536
#define CCH 512
#define GDIM 66
#define GDIM2 (66*66)
#define CAPO 18432          // per-offset compacted-row capacity
#define TPO1 144            // 128-row tiles per offset = CAPO/128

__device__ __forceinline__ u16 f2bf(float f) {
    u32 u = __builtin_bit_cast(u32, f);
    u32 r = (u + 0x7fffu + ((u >> 16) & 1u)) >> 16;
    return (u16)r;
}
__device__ __forceinline__ float bf2f(u16 h) {
    u32 u = ((u32)h) << 16;
    return __builtin_bit_cast(float, u);
}
__device__ __forceinline__ void gld16(const void* g, void* l) {
    __builtin_amdgcn_global_load_lds((const __attribute__((address_space(1))) void*)g,
                                     (__attribute__((address_space(3))) void*)l, 16, 0, 0);
}

// ---------------- setup kernels ----------------

__global__ void scatter_vox(const int* __restrict__ coords, int* __restrict__ grid) {
    int i = blockIdx.x * 256 + threadIdx.x;
    if (i < NPTS) {
        int c0 = coords[3*i], c1 = coords[3*i+1], c2 = coords[3*i+2];
        grid[(c0+1)*GDIM2 + (c1+1)*GDIM + (c2+1)] = i;
    }
}

__global__ void cast_bf16(const float* __restrict__ in, u16* __restrict__ out, int n8) {
    int i = blockIdx.x * 256 + threadIdx.x;
    if (i >= n8) return;
    f4v a = *(const f4v*)(in + (size_t)i*8);
    f4v b = *(const f4v*)(in + (size_t)i*8 + 4);
    short8 o;
    #pragma unroll
    for (int j = 0; j < 4; ++j) { o[j] = (short)f2bf(a[j]); o[j+4] = (short)f2bf(b[j]); }
    *(short8*)(out + (size_t)i*8) = o;
}

// in: f32 [R][Cc] row-major, out: bf16 [Cc][R]
__global__ void transpose_cast(const float* __restrict__ in, u16* __restrict__ out,
                               int R, int Cc) {
    __shared__ float tile[32][33];
    size_t moff = (size_t)blockIdx.z * R * Cc;
    in += moff; out += moff;
    int tx = threadIdx.x, ty = threadIdx.y;
    #pragma unroll
    for (int j = 0; j < 4; ++j) {
        int r = blockIdx.y*32 + ty + j*8;
        int c = blockIdx.x*32 + tx;
        tile[ty + j*8][tx] = in[(size_t)r*Cc + c];
    }
    __syncthreads();
    #pragma unroll
    for (int j = 0; j < 4; ++j) {
        int orow = blockIdx.x*32 + ty + j*8;
        int ocol = blockIdx.y*32 + tx;
        out[(size_t)orow*R + ocol] = f2bf(tile[tx][ty + j*8]);
    }
}

// ---------------- compaction: count -> scan -> fill (+ inverse posMap) ----------------

__device__ __forceinline__ int nbr_lookup(const int* coords, const int* grid, int i, int o) {
    int dx = o / 9, dy = (o / 3) % 3, dz = o % 3;
    int c0 = coords[3*i], c1 = coords[3*i+1], c2 = coords[3*i+2];
    return grid[(c0+dx)*GDIM2 + (c1+dy)*GDIM + (c2+dz)];
}

__global__ __launch_bounds__(256) void count_valid(const int* __restrict__ coords,
        const int* __restrict__ grid, int* __restrict__ blockCnt) {
    int o1 = blockIdx.y;
    int o = o1 + (o1 >= 13);
    int i = blockIdx.x*256 + threadIdx.x;
    int v = nbr_lookup(coords, grid, i, o);
    unsigned long long b = __ballot(v >= 0);
    __shared__ int wc[4];
    if ((threadIdx.x & 63) == 0) wc[threadIdx.x >> 6] = __popcll(b);
    __syncthreads();
    if (threadIdx.x == 0)
        blockCnt[o1*256 + blockIdx.x] = wc[0]+wc[1]+wc[2]+wc[3];
}

__global__ __launch_bounds__(256) void scan_kernel(const int* __restrict__ blockCnt,
        int* __restrict__ blockOff, int* __restrict__ cnt) {
    int t = threadIdx.x, lane = t & 63, w = t >> 6;
    __shared__ int wsum[4];
    for (int o1 = 0; o1 < 26; ++o1) {
        int v = blockCnt[o1*256 + t];
        int x = v;
        #pragma unroll
        for (int s = 1; s < 64; s <<= 1) {
            int y = __shfl_up(x, s);
            if (lane >= s) x += y;
        }
        if (lane == 63) wsum[w] = x;
        __syncthreads();
        int base = 0;
        for (int k = 0; k < w; ++k) base += wsum[k];
        blockOff[o1*256 + t] = base + x - v;
        if (t == 255) cnt[o1] = base + x;
        __syncthreads();
    }
}

__global__ __launch_bounds__(256) void fill_kernel(const int* __restrict__ coords,
        const int* __restrict__ grid, const int* __restrict__ blockOff,
        int* __restrict__ srcIdx, int* __restrict__ posMap) {
    int o1 = blockIdx.y;
    int o = o1 + (o1 >= 13);
    int i = blockIdx.x*256 + threadIdx.x;
    int v = nbr_lookup(coords, grid, i, o);
    bool valid = v >= 0;
    unsigned long long b = __ballot(valid);
    int lane = threadIdx.x & 63, w = threadIdx.x >> 6;
    __shared__ int wc[4];
    if (lane == 0) wc[w] = __popcll(b);
    __syncthreads();
    int base = blockOff[o1*256 + blockIdx.x];
    for (int k = 0; k < w; ++k) base += wc[k];
    int pre = __popcll(b & ((1ull << lane) - 1ull));
    int pos = base + pre;
    bool ok = valid && pos < CAPO;
    if (ok) srcIdx[o1*CAPO + pos] = v;
    posMap[(size_t)o1*NPTS + i] = ok ? pos : -1;
}

// ============ m97-style 128x128 GEMM engine: 4 waves, 32KB LDS, 2 barriers/K-step ====
// High occupancy (4-5 blocks/CU) -> inter-block overlap hides barrier drains.
// MODE 1: mlp1 — outb bf16 = silu(acc+bias)
// MODE 2: mlp2 — outf f32 = acc+bias+resid (first) or acc+outf
// MODE 3: conv center — outb bf16 = acc+bias
// XCD-grouped map: NX col-tiles of one row-panel on one XCD (L2 A-reuse).

template<int MODE, int NX>
__global__ __launch_bounds__(256, 4) void gemm128(
    const u16* __restrict__ A, int lda,
    const u16* __restrict__ BT, int ldb,
    int nT,
    const float* __restrict__ bias,
    const float* __restrict__ resid,
    float* __restrict__ outf, u16* __restrict__ outb, int ldout, int first)
{
    __shared__ __align__(1024) char ldsA[16384];
    __shared__ __align__(1024) char ldsB[16384];
    const int L = blockIdx.x;
    const int cx = L & 7, tt0 = L >> 3;
    const int bx = tt0 % NX;
    const int by = cx + 8 * (tt0 / NX);
    const int row0 = by * 128, col0 = bx * 128;

    const int t = threadIdx.x;
    const int w = t >> 6, lane = t & 63;
    const int wm = w >> 1, wn = w & 1;
    const int ccsrc = (lane & 7) ^ (lane >> 3);
    const int laneRow = lane >> 3;

    f32x4 acc[4][4] = {};

    const u16* aptr[4];
    const u16* bptr[4];
    #pragma unroll
    for (int it = 0; it < 4; ++it) {
        int r = w*32 + it*8 + laneRow;
        aptr[it] = A + (size_t)(row0 + r)*lda + ccsrc*8;
        bptr[it] = BT + (size_t)(col0 + r)*ldb + ccsrc*8;
    }

    #pragma unroll 1
    for (int ks = 0; ks < nT; ++ks) {
        int k0 = ks * 64;
        #pragma unroll
        for (int it = 0; it < 4; ++it) {
            int c = w*256 + it*64 + lane;
            gld16(aptr[it] + k0, ldsA + c*16);
            gld16(bptr[it] + k0, ldsB + c*16);
        }
        __syncthreads();
        #pragma unroll
        for (int kk = 0; kk < 2; ++kk) {
            short8 a[4], b[4];
            #pragma unroll
            for (int f = 0; f < 4; ++f) {
                int rowA = wm*64 + f*16 + (lane & 15);
                int ch = (kk*4 + (lane >> 4)) ^ (lane & 7);
                a[f] = *(const short8*)(void*)(ldsA + rowA*128 + ch*16);
                int rowB = wn*64 + f*16 + (lane & 15);
                b[f] = *(const short8*)(void*)(ldsB + rowB*128 + ch*16);
            }
            #pragma unroll
            for (int i = 0; i < 4; ++i)
                #pragma unroll
                for (int j = 0; j < 4; ++j)
                    acc[i][j] = __builtin_amdgcn_mfma_f32_16x16x32_bf16(a[i], b[j], acc[i][j], 0, 0, 0);
        }
        __syncthreads();
    }

    #pragma unroll
    for (int i = 0; i < 4; ++i) {
        int r = row0 + wm*64 + i*16 + (lane >> 4)*4;
        #pragma unroll
        for (int j = 0; j < 4; ++j) {
            int c = col0 + wn*64 + j*16 + (lane & 15);
            float bv = bias[c];
            #pragma unroll
            for (int q = 0; q < 4; ++q) {
                float v = acc[i][j][q];
                if constexpr (MODE == 1) {
                    float val = v + bv;
                    float sg = 1.f / (1.f + __expf(-val));
                    outb[(size_t)(r+q)*ldout + c] = f2bf(val * sg);
                } else if constexpr (MODE == 2) {
                    size_t ix = (size_t)(r+q)*512 + c;
                    outf[ix] = first ? (v + bv + resid[ix]) : (v + outf[ix]);
                } else {  // MODE 3
                    outb[(size_t)(r+q)*ldout + c] = f2bf(v + bv);
                }
            }
        }
    }
}

// comp GEMM: compacted rows -> bf16 contribution rows (no atomics), 128x128 engine.
// grid 1-D = 4 coltiles * TPO1 * 13, XCD-grouped: 4 col-tiles of one (offset,mt) on one XCD.
__global__ __launch_bounds__(256, 4) void comp_gemm(
    const u16* __restrict__ fb,
    const int* __restrict__ srcIdx,
    const int* __restrict__ cnt,
    const u16* __restrict__ wcT,
    u16* __restrict__ comp,
    int o1base)
{
    __shared__ __align__(1024) char ldsA[16384];
    __shared__ __align__(1024) char ldsB[16384];
    const int L = blockIdx.x;
    const int cx = L & 7, tt0 = L >> 3;
    const int bx = tt0 & 3;                 // col tile (4 x 128)
    const int y  = cx + 8 * (tt0 >> 2);     // 0..13*TPO1-1
    const int o1loc = y / TPO1, mt = y % TPO1;
    const int o1 = o1base + o1loc;
    const int n = cnt[o1];
    if (mt * 128 >= n) return;              // block-uniform, before any barrier
    const int o = o1 + (o1 >= 13);
    const int t = threadIdx.x;
    const int w = t >> 6, lane = t & 63;
    const int wm = w >> 1, wn = w & 1;
    const int col0 = bx * 128;
    const int ccsrc = (lane & 7) ^ (lane >> 3);
    const int laneRow = lane >> 3;

    const int* sIdx = srcIdx + o1*CAPO + mt*128;
    const u16* wb = wcT + ((size_t)o << 18);

    const u16* aptr[4];
    const u16* bptr[4];
    #pragma unroll
    for (int it = 0; it < 4; ++it) {
        int rloc = w*32 + it*8 + laneRow;
        int src = (mt*128 + rloc < n) ? sIdx[rloc] : NPTS;   // zero-row fallback
        aptr[it] = fb + (size_t)src*512 + ccsrc*8;
        bptr[it] = wb + (size_t)(col0 + rloc)*512 + ccsrc*8;
    }

    f32x4 acc[4][4] = {};

    #pragma unroll 1
    for (int ks = 0; ks < 8; ++ks) {
        int k0 = ks * 64;
        #pragma unroll
        for (int it = 0; it < 4; ++it) {
            int c = w*256 + it*64 + lane;
            gld16(aptr[it] + k0, ldsA + c*16);
            gld16(bptr[it] + k0, ldsB + c*16);
        }
        __syncthreads();
        #pragma unroll
        for (int kk = 0; kk < 2; ++kk) {
            short8 a[4], b[4];
            #pragma unroll
            for (int f = 0; f < 4; ++f) {
                int rowA = wm*64 + f*16 + (lane & 15);
                int ch = (kk*4 + (lane >> 4)) ^ (lane & 7);
                a[f] = *(const short8*)(void*)(ldsA + rowA*128 + ch*16);
                int rowB = wn*64 + f*16 + (lane & 15);
                b[f] = *(const short8*)(void*)(ldsB + rowB*128 + ch*16);
            }
            #pragma unroll
            for (int i = 0; i < 4; ++i)
                #pragma unroll
                for (int j = 0; j < 4; ++j)
                    acc[i][j] = __builtin_amdgcn_mfma_f32_16x16x32_bf16(a[i], b[j], acc[i][j], 0, 0, 0);
        }
        __syncthreads();
    }

    #pragma unroll
    for (int i = 0; i < 4; ++i) {
        #pragma unroll
        for (int q = 0; q < 4; ++q) {
            int rl = wm*64 + i*16 + (lane >> 4)*4 + q;
            if (mt*128 + rl < n) {
                u16* cr = comp + ((size_t)(o1loc*CAPO + mt*128 + rl))*512
                               + col0 + wn*64 + (lane & 15);
                #pragma unroll
                for (int j = 0; j < 4; ++j)
                    cr[j*16] = f2bf(acc[i][j][q]);
            }
        }
    }
}

// ---------------- gather-reduce: h(bf16) += contributions; FINAL fuses LN ----------------

template<int FINAL>
__global__ __launch_bounds__(512) void reduce_kernel(
    const u16* __restrict__ comp, const int* __restrict__ posMap,
    int o1base, int nOff,
    u16* __restrict__ h,
    const float* __restrict__ g, const float* __restrict__ bb,
    u16* __restrict__ nf)
{
    int w = threadIdx.x >> 6, lane = threadIdx.x & 63;
    int i = blockIdx.x*8 + w;
    u16* hr = h + (size_t)i*512 + lane*8;
    short8 hv = *(const short8*)hr;
    float x[8];
    #pragma unroll
    for (int j = 0; j < 8; ++j) x[j] = bf2f((u16)hv[j]);

    #pragma unroll 1
    for (int k = 0; k < nOff; ++k) {
        int pos = posMap[(size_t)(o1base + k)*NPTS + i];
        if (pos >= 0) {   // wave-uniform branch
            short8 cv = *(const short8*)(comp + ((size_t)(k*CAPO + pos))*512 + lane*8);
            #pragma unroll
            for (int j = 0; j < 8; ++j) x[j] += bf2f((u16)cv[j]);
        }
    }

    if constexpr (!FINAL) {
        short8 o;
        #pragma unroll
        for (int j = 0; j < 8; ++j) o[j] = (short)f2bf(x[j]);
        *(short8*)hr = o;
    } else {
        float s = 0.f, ss = 0.f;
        #pragma unroll
        for (int j = 0; j < 8; ++j) { s += x[j]; ss += x[j]*x[j]; }
        #pragma unroll
        for (int m = 1; m < 64; m <<= 1) { s += __shfl_xor(s, m); ss += __shfl_xor(ss, m); }
        float mu = s * (1.f/512.f);
        float var = ss * (1.f/512.f) - mu*mu;
        float inv = rsqrtf(var + 1e-6f);
        short8 o;
        #pragma unroll
        for (int j = 0; j < 8; ++j) {
            int c = lane*8 + j;
            o[j] = (short)f2bf((x[j] - mu) * inv * g[c] + bb[c]);
        }
        *(short8*)(nf + (size_t)i*512 + lane*8) = o;
    }
}

// ---------------- launch ----------------

extern "C" void kernel_launch(void* const* d_in, const int* in_sizes, int n_in,
                              void* d_out, int out_size, void* d_ws, size_t ws_size,
                              hipStream_t stream) {
    const float* feats  = (const float*)d_in[0];
    const int*   coords = (const int*)d_in[1];
    const float* conv_w = (const float*)d_in[2];
    const float* conv_b = (const float*)d_in[3];
    const float* ln_g   = (const float*)d_in[4];
    const float* ln_b   = (const float*)d_in[5];
    const float* w1     = (const float*)d_in[6];
    const float* b1     = (const float*)d_in[7];
    const float* w2     = (const float*)d_in[8];
    const float* b2     = (const float*)d_in[9];
    float* out = (float*)d_out;
    char* ws = (char*)d_ws;

    size_t off = 0;
    auto take = [&](size_t bytes) -> void* {
        void* p = ws + off;
        off += (bytes + 1023) & ~(size_t)1023;
        return p;
    };
    int* grid_i   = (int*)take((size_t)GDIM*GDIM2*4);
    u16* wcT      = (u16*)take(27ull*512*512*2);
    u16* w1T      = (u16*)take(2048ull*512*2);
    u16* w2T      = (u16*)take(512ull*2048*2);
    u16* fb       = (u16*)take((NPTS+1ull)*512*2);
    int* srcIdx   = (int*)take(26ull*CAPO*4);
    int* posMap   = (int*)take(26ull*NPTS*4);
    int* blockCnt = (int*)take(26*256*4);
    int* blockOff = (int*)take(26*256*4);
    int* cnt      = (int*)take(26*4);
    u16* comp     = (u16*)take(13ull*CAPO*512*2);   // per-pass contribution rows (bf16)
    u16* h        = (u16*)take(67108864ull);        // h bf16 [N][512]
    u16* g1 = h;                                    // overlays h (dead after reduce<1>)
    bool fused = (off + 201326592ull) <= ws_size;   // need [N][2048] total for g1
    if (fused) take(201326592ull);
    else       take(67108864ull);
    u16* nf = fb;                                   // reused after conv consumes fb

    hipMemsetAsync(grid_i, 0xFF, (size_t)GDIM*GDIM2*4, stream);
    hipMemsetAsync(fb + (size_t)NPTS*512, 0, 512*2, stream);

    scatter_vox<<<NPTS/256, 256, 0, stream>>>(coords, grid_i);
    cast_bf16<<<(NPTS*CCH/8)/256, 256, 0, stream>>>(feats, fb, NPTS*CCH/8);
    transpose_cast<<<dim3(16,16,27), dim3(32,8), 0, stream>>>(conv_w, wcT, 512, 512);
    transpose_cast<<<dim3(64,16,1),  dim3(32,8), 0, stream>>>(w1, w1T, 512, 2048);
    transpose_cast<<<dim3(16,64,1),  dim3(32,8), 0, stream>>>(w2, w2T, 2048, 512);

    count_valid<<<dim3(256,26), 256, 0, stream>>>(coords, grid_i, blockCnt);
    scan_kernel<<<1, 256, 0, stream>>>(blockCnt, blockOff, cnt);
    fill_kernel<<<dim3(256,26), 256, 0, stream>>>(coords, grid_i, blockOff, srcIdx, posMap);

    // center offset (o=13): dense, writes h bf16 = fb @ W13^T + bias (h init)
    gemm128<3,4><<<2048, 256, 0, stream>>>(
        fb, 512, wcT + (13ull << 18), 512, 8, conv_b, nullptr, nullptr, h, 512, 0);

    // two passes of 13 non-center offsets: compact GEMM -> gather reduce (no atomics)
    comp_gemm<<<4*TPO1*13, 256, 0, stream>>>(fb, srcIdx, cnt, wcT, comp, 0);
    reduce_kernel<0><<<NPTS/8, 512, 0, stream>>>(comp, posMap, 0, 13, h, nullptr, nullptr, nullptr);
    comp_gemm<<<4*TPO1*13, 256, 0, stream>>>(fb, srcIdx, cnt, wcT, comp, 13);
    reduce_kernel<1><<<NPTS/8, 512, 0, stream>>>(comp, posMap, 13, 13, h, ln_g, ln_b, nf);

    if (fused) {
        // MLP1: one launch over all 2048 hidden cols -> g1 [N][2048]
        gemm128<1,16><<<8192, 256, 0, stream>>>(
            nf, 512, w1T, 512, 8, b1, nullptr, nullptr, g1, 2048, 0);
        // MLP2: single K=2048 launch, writes out once
        gemm128<2,4><<<2048, 256, 0, stream>>>(
            g1, 2048, w2T, 2048, 32, b2, feats, out, nullptr, 512, 1);
    } else {
        for (int half = 0; half < 2; ++half) {
            gemm128<1,8><<<4096, 256, 0, stream>>>(
                nf, 512, w1T + (size_t)half*1024*512, 512, 8,
                b1 + half*1024, nullptr, nullptr, g1, 1024, 0);
            gemm128<2,4><<<2048, 256, 0, stream>>>(
                g1, 1024, w2T + half*1024, 2048, 16,
                b2, feats, out, nullptr, 512, half == 0);
        }
    }
}